// Round 12
// baseline (5849.685 us; speedup 1.0000x reference)
//
#include <hip/hip_runtime.h>

typedef unsigned short u16;
typedef unsigned int u32;
typedef unsigned long long u64;
typedef short v8s __attribute__((ext_vector_type(8)));
typedef float v4f __attribute__((ext_vector_type(4)));
typedef int v4i __attribute__((ext_vector_type(4)));

#define MFMA16(a, b, c) __builtin_amdgcn_mfma_f32_16x16x32_bf16((a), (b), (c), 0, 0, 0)

#define B_ 32
#define T_ 128
#define H_ 1024
#define A_ 1024
#define E_ 512
#define V_ 512
#define NBLK 256
#define NTH 512
#define ENC_LDS_BYTES 131072
#define SCRATCH_BYTES 28672
#define DSMEM_BYTES (ENC_LDS_BYTES + SCRATCH_BYTES)

__device__ __forceinline__ float b2f(u16 u) {
  union { u32 u; float f; } c; c.u = ((u32)u) << 16; return c.f;
}
__device__ __forceinline__ u16 f2b(float f) {
  union { float f; u32 u; } c; c.f = f;
  u32 x = c.u;
  x += 0x7fffu + ((x >> 16) & 1u);
  return (u16)(x >> 16);
}

// ---- relaxed agent-scope (sc1, write-through to coherence point) ----
__device__ __forceinline__ void ato_st(u32* p, u32 v) {
  __hip_atomic_store(p, v, __ATOMIC_RELAXED, __HIP_MEMORY_SCOPE_AGENT);
}
__device__ __forceinline__ void ato_stf(float* p, float v) {
  union { float f; u32 u; } c; c.f = v; ato_st((u32*)p, c.u);
}
__device__ __forceinline__ void ato_addf(float* p, float v) {
  __hip_atomic_fetch_add(p, v, __ATOMIC_RELAXED, __HIP_MEMORY_SCOPE_AGENT);
}

// ---- issue-early sc1 loads (L2-bypass, compiler-invisible -> pipelined) ----
__device__ __forceinline__ v4i ld16_sc1(const void* p) {
  v4i r;
  asm volatile("global_load_dwordx4 %0, %1, off sc1" : "=v"(r) : "v"(p));
  return r;
}
__device__ __forceinline__ float ld4_sc1(const void* p) {
  float r;
  asm volatile("global_load_dword %0, %1, off sc1" : "=v"(r) : "v"(p));
  return r;
}
__device__ __forceinline__ void wait_vm0() {
  asm volatile("s_waitcnt vmcnt(0)" ::: "memory");
  __builtin_amdgcn_sched_barrier(0);
}
__device__ __forceinline__ v8s as8(v4i x) { union { v4i a; v8s b; } u; u.a = x; return u.b; }
// 8 f32 (bias folded) -> relu -> split bf16 hi/lo fragments
__device__ __forceinline__ void cvt8(v4i qa, v4i qb, v8s& hi, v8s& lo) {
  union { v4i q; float f[4]; } a, b;
  a.q = qa; b.q = qb;
  float v[8] = {a.f[0], a.f[1], a.f[2], a.f[3], b.f[0], b.f[1], b.f[2], b.f[3]};
  u16 hh[8], ll[8];
  #pragma unroll
  for (int i = 0; i < 8; ++i) {
    float x = fmaxf(v[i], 0.f);
    u16 hv = f2b(x);
    hh[i] = hv; ll[i] = f2b(x - b2f(hv));
  }
  hi = *(v8s*)hh; lo = *(v8s*)ll;
}

// Dense-slot grid barrier: 256 consecutive u32 (4 cache lines). Lane i polls
// slots[i]; a polling wave touches ONE 64B line per round (4 lines/block)
// instead of 256 spread lines -> ~64x less poll traffic, same hop count.
__device__ __forceinline__ void grid_bar(u32* slots, u32 ep) {
  asm volatile("s_waitcnt vmcnt(0)" ::: "memory");
  __syncthreads();
  if (threadIdx.x == 0)
    __hip_atomic_store(slots + blockIdx.x, ep, __ATOMIC_RELAXED, __HIP_MEMORY_SCOPE_AGENT);
  if (threadIdx.x < NBLK) {
    while (__hip_atomic_load(slots + threadIdx.x, __ATOMIC_RELAXED, __HIP_MEMORY_SCOPE_AGENT) < ep)
      __builtin_amdgcn_s_sleep(2);
  }
  __syncthreads();
  asm volatile("" ::: "memory");
}

// GEMM inner (plain loads; used by dec pre-GEMM)
__device__ __forceinline__ void gemm_nk(const u16* ah, const u16* al, size_t mstr,
                                        const u16* bp, int nk, v4f& c0, v4f& c1) {
  #pragma unroll 2
  for (int i = 0; i < nk; ++i) {
    v8s b   = *(const v8s*)(bp);
    v8s a0h = *(const v8s*)(ah);
    v8s a1h = *(const v8s*)(ah + mstr);
    v8s a0l = *(const v8s*)(al);
    v8s a1l = *(const v8s*)(al + mstr);
    c0 = MFMA16(a0h, b, c0);
    c1 = MFMA16(a1h, b, c1);
    c0 = MFMA16(a0l, b, c0);
    c1 = MFMA16(a1l, b, c1);
    ah += 32; al += 32; bp += 32;
  }
}

// partial layout: [wave][lane][8] floats
__device__ __forceinline__ void red_store2(float* part, int wv, int lane, v4f c0, v4f c1) {
  float* p = part + (wv * 64 + lane) * 8;
  #pragma unroll
  for (int r = 0; r < 4; ++r) { p[r] = c0[r]; p[4 + r] = c1[r]; }
}
__device__ __forceinline__ float red_sum2(const float* part, int o) {
  int m = o >> 4, n = o & 15;
  int lane = (((m & 15) >> 2) << 4) + n;
  int idx = ((m >> 4) << 2) + (m & 3);
  float s = 0.f;
  #pragma unroll
  for (int w = 0; w < 8; ++w) s += part[(w * 64 + lane) * 8 + idx];
  return s;
}

__global__ void __launch_bounds__(NTH, 1)
dec_persist(const u16* __restrict__ WattT, const u16* __restrict__ Whh_b,
            const u16* __restrict__ Wih_b, const u16* __restrict__ Wc_ctxT,
            const float* __restrict__ enc_f,
            const float* __restrict__ bih, const float* __restrict__ bhh,
            const float* __restrict__ ldec_all,
            float* h, float* logit, float* gh, float* g_all,
            u16* hs_hi, u16* hs_lo, u32* bar)
{
  const int tid = threadIdx.x;
  const int bid = blockIdx.x;
  const int lane = tid & 63;
  const int wv = tid >> 6;
  const int ln = lane & 15;
  const int kq8 = (lane >> 4) * 8;

  extern __shared__ __align__(16) unsigned char dsm[];
  u16* lds_enc = (u16*)dsm;                        // [1024][64] bf16 = 128KB
  float* scratch = (float*)(dsm + ENC_LDS_BYTES);  // 28KB

  // ---- one-time: stage this block's enc slice (b=bid>>3, e0=(bid&7)*64) ----
  {
    int b = bid >> 3, e0 = (bid & 7) * 64;
    const float* src = enc_f + (size_t)b * A_ * E_ + e0 + (tid & 7) * 8;
    int seg = (tid & 7) * 8;
    for (int i = 0; i < 16; ++i) {
      int row = i * 64 + (tid >> 3);
      const float* sp = src + (size_t)row * E_;
      float4 a = *(const float4*)sp;
      float4 bq = *(const float4*)(sp + 4);
      u16 tmp[8] = {f2b(a.x), f2b(a.y), f2b(a.z), f2b(a.w),
                    f2b(bq.x), f2b(bq.y), f2b(bq.z), f2b(bq.w)};
      *(v8s*)(lds_enc + row * 64 + seg) = *(v8s*)tmp;
    }
  }

  u32 ep = 0;

  for (int t = 0; t < T_; ++t) {
    // ==== P1: 128 active blocks, 32 cols each (A-frags shared across 2 tiles)
    //      blocks 0-31: logits (n0=bid*32); 32-127: gh (j0=(bid-32)*32) ====
    if (bid < 128) {
      float* part = scratch;
      const u16* hb = hs_hi + (size_t)t * (B_ * H_);
      const u16* lb = hs_lo + (size_t)t * (B_ * H_);
      size_t a0 = (size_t)ln * H_ + wv * 128 + kq8;
      v4i ah0[4], ah1[4], al0[4], al1[4];
      #pragma unroll
      for (int i = 0; i < 4; ++i) {
        ah0[i] = ld16_sc1(hb + a0 + i * 32);
        ah1[i] = ld16_sc1(hb + a0 + 16 * H_ + i * 32);
        al0[i] = ld16_sc1(lb + a0 + i * 32);
        al1[i] = ld16_sc1(lb + a0 + 16 * H_ + i * 32);
      }
      const u16* bpA;
      size_t bstride;
      float ldec0 = 0.f, ldec1 = 0.f;
      int n0;
      if (bid < 32) {
        n0 = bid * 32;
        const float* lp = ldec_all + (size_t)t * (B_ * A_) + (tid >> 4) * A_ + n0 + (tid & 15);
        ldec0 = lp[0];
        ldec1 = lp[16];
        bpA = WattT + (size_t)(n0 + ln) * 2048 + 1024 + wv * 128 + kq8;
        bstride = 2048;
      } else {
        n0 = (bid - 32) * 32;
        bpA = Whh_b + (size_t)(n0 + ln) * H_ + wv * 128 + kq8;
        bstride = H_;
      }
      const u16* bpB = bpA + 16 * bstride;
      v8s wA[4], wB[4];
      #pragma unroll
      for (int i = 0; i < 4; ++i) {
        wA[i] = *(const v8s*)(bpA + i * 32);
        wB[i] = *(const v8s*)(bpB + i * 32);
      }
      v4f cA0 = {0.f,0.f,0.f,0.f}, cA1 = cA0, cB0 = cA0, cB1 = cA0;
      wait_vm0();
      #pragma unroll
      for (int i = 0; i < 4; ++i) {
        v8s h0 = as8(ah0[i]), h1 = as8(ah1[i]);
        v8s l0 = as8(al0[i]), l1 = as8(al1[i]);
        cA0 = MFMA16(h0, wA[i], cA0); cA1 = MFMA16(h1, wA[i], cA1);
        cA0 = MFMA16(l0, wA[i], cA0); cA1 = MFMA16(l1, wA[i], cA1);
        cB0 = MFMA16(h0, wB[i], cB0); cB1 = MFMA16(h1, wB[i], cB1);
        cB0 = MFMA16(l0, wB[i], cB0); cB1 = MFMA16(l1, wB[i], cB1);
      }
      // round A (cols n0..n0+15)
      red_store2(part, wv, lane, cA0, cA1);
      __syncthreads();
      {
        float s = red_sum2(part, tid);
        int m = tid >> 4, n = tid & 15;
        if (bid < 32) ato_stf(&logit[m * A_ + n0 + n], s + ldec0);
        else          ato_stf(&gh[(size_t)(n0 + n) * 32 + m], s + bhh[n0 + n]);
      }
      __syncthreads();
      // round B (cols n0+16..n0+31)
      red_store2(part, wv, lane, cB0, cB1);
      __syncthreads();
      {
        float s = red_sum2(part, tid);
        int m = tid >> 4, n = tid & 15;
        if (bid < 32) ato_stf(&logit[m * A_ + n0 + 16 + n], s + ldec1);
        else          ato_stf(&gh[(size_t)(n0 + 16 + n) * 32 + m], s + bhh[n0 + 16 + n]);
      }
    }
    grid_bar(bar, ++ep);

    // ==== P2: softmax + ctx (LDS enc) + coalesced GEMV add into g_all[t] ====
    {
      float* p    = scratch;            // [1024]
      float* part = scratch + 1024;     // [64][64]
      float* red  = scratch + 5120;     // [16]
      float* sctx = scratch + 5136;     // [64]
      int b = bid >> 3, es = bid & 7;
      float v1 = ld4_sc1(&logit[b * A_ + tid]);
      float v2 = ld4_sc1(&logit[b * A_ + 512 + tid]);
      wait_vm0();
      float mx = fmaxf(v1, v2);
      #pragma unroll
      for (int off = 32; off; off >>= 1) mx = fmaxf(mx, __shfl_xor(mx, off));
      if (lane == 0) red[wv] = mx;
      __syncthreads();
      float mfull = red[0];
      #pragma unroll
      for (int q = 1; q < 8; ++q) mfull = fmaxf(mfull, red[q]);
      float e1 = __expf(v1 - mfull), e2 = __expf(v2 - mfull);
      p[tid] = e1; p[512 + tid] = e2;
      float sm = e1 + e2;
      #pragma unroll
      for (int off = 32; off; off >>= 1) sm += __shfl_xor(sm, off);
      if (lane == 0) red[8 + wv] = sm;
      __syncthreads();
      float ssum = red[8];
      #pragma unroll
      for (int q = 1; q < 8; ++q) ssum += red[8 + q];
      float inv = 1.f / ssum;

      int le = lane & 7, lr = lane >> 3;
      float acc[8] = {0.f, 0.f, 0.f, 0.f, 0.f, 0.f, 0.f, 0.f};
      #pragma unroll 4
      for (int i = 0; i < 16; ++i) {
        int l = i * 64 + wv * 8 + lr;
        v8s w = *(const v8s*)(lds_enc + l * 64 + le * 8);
        float pv = p[l];
        #pragma unroll
        for (int r = 0; r < 8; ++r) acc[r] += pv * b2f((u16)w[r]);
      }
      float* pp = part + ((wv * 8 + lr) * 8 + le) * 8;
      #pragma unroll
      for (int r = 0; r < 8; ++r) pp[r] = acc[r];
      __syncthreads();
      if (tid < 64) {
        int eo = tid >> 3, r = tid & 7;
        float s = 0.f;
        #pragma unroll
        for (int q = 0; q < 64; ++q) s += part[q * 64 + eo * 8 + r];
        sctx[tid] = s * inv;
      }
      __syncthreads();
      // GEMV (transposed weights): thread -> cols 2*tid, 2*tid+1; contiguous e
      {
        const u16* w0 = Wc_ctxT + (size_t)(2 * tid) * E_ + es * 64;
        const u16* w1 = w0 + E_;
        float a0 = 0.f, a1 = 0.f;
        #pragma unroll
        for (int i = 0; i < 8; ++i) {
          v8s q0 = *(const v8s*)(w0 + i * 8);
          v8s q1 = *(const v8s*)(w1 + i * 8);
          #pragma unroll
          for (int r = 0; r < 8; ++r) {
            float pv = sctx[i * 8 + r];
            a0 += pv * b2f((u16)q0[r]);
            a1 += pv * b2f((u16)q1[r]);
          }
        }
        float* gp = g_all + (size_t)t * (B_ * H_) + b * H_ + 2 * tid;
        ato_addf(gp, a0);
        ato_addf(gp + 1, a1);
      }
    }
    grid_bar(bar, ++ep);

    // ==== P3: gates only (blocks 0-63); issue-early sc1 g/gh loads ====
    {
      if (bid < 64) {
        float* part = scratch;            // [8][64][12] = 24KB per pass
        float* hx   = scratch + 6144;     // [32][16]
        int j0 = bid * 16;
        const float* gbase = g_all + (size_t)t * (B_ * H_);
        int koff0 = wv * 128 + kq8;
        v4i gr0[8], gr1[8];
        #pragma unroll
        for (int i = 0; i < 4; ++i) {
          const float* p0 = gbase + (size_t)ln * H_ + koff0 + i * 32;
          const float* p1 = gbase + (size_t)(ln + 16) * H_ + koff0 + i * 32;
          gr0[2 * i]     = ld16_sc1(p0);
          gr0[2 * i + 1] = ld16_sc1(p0 + 4);
          gr1[2 * i]     = ld16_sc1(p1);
          gr1[2 * i + 1] = ld16_sc1(p1 + 4);
        }
        const u16* bp0 = Wih_b + (size_t)(j0 + ln) * H_ + koff0;
        const u16* bp1 = bp0 + (size_t)H_ * H_;
        const u16* bp2 = bp0 + (size_t)2 * H_ * H_;
        v8s wb0[4], wb1[4], wb2[4];
        #pragma unroll
        for (int i = 0; i < 4; ++i) {
          wb0[i] = *(const v8s*)(bp0 + i * 32);
          wb1[i] = *(const v8s*)(bp1 + i * 32);
          wb2[i] = *(const v8s*)(bp2 + i * 32);
        }
        v4f c00 = {0.f,0.f,0.f,0.f}, c01 = c00, c02 = c00, c10 = c00, c11 = c00, c12 = c00;
        wait_vm0();
        #pragma unroll
        for (int i = 0; i < 4; ++i) {
          v8s a0h, a0l, a1h, a1l;
          cvt8(gr0[2 * i], gr0[2 * i + 1], a0h, a0l);
          cvt8(gr1[2 * i], gr1[2 * i + 1], a1h, a1l);
          c00 = MFMA16(a0h, wb0[i], c00); c00 = MFMA16(a0l, wb0[i], c00);
          c01 = MFMA16(a0h, wb1[i], c01); c01 = MFMA16(a0l, wb1[i], c01);
          c02 = MFMA16(a0h, wb2[i], c02); c02 = MFMA16(a0l, wb2[i], c02);
          c10 = MFMA16(a1h, wb0[i], c10); c10 = MFMA16(a1l, wb0[i], c10);
          c11 = MFMA16(a1h, wb1[i], c11); c11 = MFMA16(a1l, wb1[i], c11);
          c12 = MFMA16(a1h, wb2[i], c12); c12 = MFMA16(a1l, wb2[i], c12);
        }
        // gate-side gh loads issued early (consumed after LDS reductions)
        float hr0 = 0.f, hz0 = 0.f, hn0 = 0.f, hr1 = 0.f, hz1 = 0.f, hn1 = 0.f;
        float ho0 = 0.f, ho1 = 0.f;
        int obl = tid >> 4, jj = tid & 15, j = j0 + jj;
        if (tid < 256) {
          hr0 = ld4_sc1(&gh[(size_t)j * 32 + obl]);
          hz0 = ld4_sc1(&gh[(size_t)(H_ + j) * 32 + obl]);
          hn0 = ld4_sc1(&gh[(size_t)(2 * H_ + j) * 32 + obl]);
          hr1 = ld4_sc1(&gh[(size_t)j * 32 + 16 + obl]);
          hz1 = ld4_sc1(&gh[(size_t)(H_ + j) * 32 + 16 + obl]);
          hn1 = ld4_sc1(&gh[(size_t)(2 * H_ + j) * 32 + 16 + obl]);
          ho0 = h[obl * H_ + j];
          ho1 = h[(obl + 16) * H_ + j];
        }
        float bi_r = 0.f, bi_z = 0.f, bi_n = 0.f;
        if (tid < 256) {
          bi_r = bih[j]; bi_z = bih[H_ + j]; bi_n = bih[2 * H_ + j];
        }
        #pragma unroll
        for (int pass = 0; pass < 2; ++pass) {
          float* pp = part + (wv * 64 + lane) * 12;
          if (pass == 0) {
            #pragma unroll
            for (int r = 0; r < 4; ++r) { pp[r] = c00[r]; pp[4 + r] = c01[r]; pp[8 + r] = c02[r]; }
          } else {
            #pragma unroll
            for (int r = 0; r < 4; ++r) { pp[r] = c10[r]; pp[4 + r] = c11[r]; pp[8 + r] = c12[r]; }
          }
          __syncthreads();
          if (tid < 256) {
            if (pass == 0) wait_vm0();
            int ob = pass * 16 + obl;
            int lanei = ((obl >> 2) << 4) + jj;
            int rg = obl & 3;
            float ir = 0.f, iz = 0.f, in_ = 0.f;
            #pragma unroll
            for (int w = 0; w < 8; ++w) {
              const float* q = part + (w * 64 + lanei) * 12;
              ir += q[rg]; iz += q[4 + rg]; in_ += q[8 + rg];
            }
            ir += bi_r; iz += bi_z; in_ += bi_n;
            float hr = pass ? hr1 : hr0;
            float hz = pass ? hz1 : hz0;
            float hn = pass ? hn1 : hn0;
            float ho = pass ? ho1 : ho0;
            float r = 1.f / (1.f + __expf(-(ir + hr)));
            float z = 1.f / (1.f + __expf(-(iz + hz)));
            float n = tanhf(in_ + r * hn);
            float hnew = (1.f - z) * n + z * ho;
            h[ob * H_ + j] = hnew;
            hx[ob * 16 + jj] = hnew;
          }
          __syncthreads();
        }
        if (tid < 256) {
          int ob2 = tid >> 3, j2 = (tid & 7) * 2;
          float v0 = hx[ob2 * 16 + j2], v1 = hx[ob2 * 16 + j2 + 1];
          u16 h0 = f2b(v0), h1 = f2b(v1);
          u16 l0 = f2b(v0 - b2f(h0)), l1 = f2b(v1 - b2f(h1));
          size_t idx = (size_t)(t + 1) * (B_ * H_) + ob2 * H_ + j0 + j2;
          ato_st((u32*)(hs_hi + idx), (u32)h0 | ((u32)h1 << 16));
          ato_st((u32*)(hs_lo + idx), (u32)l0 | ((u32)l1 << 16));
        }
      }
    }
    grid_bar(bar, ++ep);
  }
}

// Pre-GEMM: out[t][b][n] = dec(t,b) @ W_dec + bias  (dec(t,b)=tgt[b][t-1]; t=0 -> bias)
__global__ void __launch_bounds__(256)
dec_gemm(const u16* __restrict__ th, const u16* __restrict__ tl,
         const u16* __restrict__ W, const unsigned long wstride,
         const float* __restrict__ bias, float* __restrict__ out)
{
  int tid = threadIdx.x, lane = tid & 63, wv = tid >> 6;
  int ln = lane & 15, kq8 = (lane >> 4) * 8;
  int t = blockIdx.x >> 4, nt = blockIdx.x & 15;
  float* op = out + (size_t)t * (32 * 1024);
  if (t == 0) {
    for (int i = tid; i < 32 * 64; i += 256) {
      int b = i >> 6, n = nt * 64 + (i & 63);
      ato_stf(&op[(size_t)b * 1024 + n], bias[n]);
    }
    return;
  }
  int n0w = nt * 64 + wv * 16;
  const u16* ah = th + ((size_t)ln * T_ + (t - 1)) * H_ + kq8;
  const u16* al = tl + ((size_t)ln * T_ + (t - 1)) * H_ + kq8;
  const u16* bp = W + (size_t)(n0w + ln) * wstride + kq8;
  v4f c0 = {0.f, 0.f, 0.f, 0.f}, c1 = {0.f, 0.f, 0.f, 0.f};
  gemm_nk(ah, al, (size_t)16 * T_ * H_, bp, 32, c0, c1);
  int n = n0w + (lane & 15);
  float bo = bias[n];
  int rb = (lane >> 4) * 4;
  #pragma unroll
  for (int r = 0; r < 4; ++r) {
    ato_stf(&op[(size_t)(rb + r) * 1024 + n], c0[r] + bo);
    ato_stf(&op[(size_t)(rb + r + 16) * 1024 + n], c1[r] + bo);
  }
}

// out[b][t][v] = hseq[t*32+b][:] @ WoutT^T + bout   (M=4096, N=512, K=1024)
__global__ void __launch_bounds__(256, 2)
out_gemm(const u16* __restrict__ hseq, const u16* __restrict__ WoutT,
         const float* __restrict__ bout, float* __restrict__ out)
{
  int tid = threadIdx.x, lane = tid & 63, wv = tid >> 6;
  int ln = lane & 15, kq8 = (lane >> 4) * 8;
  int m0 = (blockIdx.x >> 3) * 32;
  int n0 = (blockIdx.x & 7) * 64 + wv * 16;
  v4f c0 = {0.f, 0.f, 0.f, 0.f}, c1 = {0.f, 0.f, 0.f, 0.f};
  const u16* ap = hseq + (size_t)(m0 + ln) * 1024 + kq8;
  const u16* bp = WoutT + (size_t)(n0 + ln) * 1024 + kq8;
  for (int i = 0; i < 32; ++i) {
    v8s b = *(const v8s*)bp;
    v8s a0 = *(const v8s*)ap;
    v8s a1 = *(const v8s*)(ap + 16 * 1024);
    c0 = MFMA16(a0, b, c0);
    c1 = MFMA16(a1, b, c1);
    ap += 32; bp += 32;
  }
  int v = n0 + ln;
  float bo = bout[v];
  int rbase = (lane >> 4) * 4;
  #pragma unroll
  for (int rg = 0; rg < 4; ++rg) {
    int m = m0 + rbase + rg;
    out[((size_t)(m & 31) * T_ + (m >> 5)) * V_ + v] = c0[rg] + bo;
    int m2 = m + 16;
    out[((size_t)(m2 & 31) * T_ + (m2 >> 5)) * V_ + v] = c1[rg] + bo;
  }
}

__global__ void __launch_bounds__(256)
hlast_copy(const float* __restrict__ h, float* __restrict__ out)
{
  int i = blockIdx.x * 256 + threadIdx.x;
  if (i < B_ * H_) out[(size_t)B_ * T_ * V_ + i] = h[i];
}

// ---------------- prep kernels ----------------
__global__ void __launch_bounds__(256)
k_cvt(const float* __restrict__ in, u16* __restrict__ out, int n)
{
  int stride = gridDim.x * 256;
  for (int i = blockIdx.x * 256 + threadIdx.x; i < n; i += stride) out[i] = f2b(in[i]);
}

__global__ void __launch_bounds__(256)
k_cvt_split(const float* __restrict__ in, u16* __restrict__ hi, u16* __restrict__ lo, int n)
{
  int stride = gridDim.x * 256;
  for (int i = blockIdx.x * 256 + threadIdx.x; i < n; i += stride) {
    float x = in[i];
    u16 a = f2b(x);
    hi[i] = a;
    lo[i] = f2b(x - b2f(a));
  }
}

// out[c][r] = bf16(in[r][c]); R, C multiples of 32
__global__ void __launch_bounds__(256)
k_tr(const float* __restrict__ in, u16* __restrict__ out, int R, int C)
{
  __shared__ float tile[32][33];
  int tc = C >> 5;
  int r0 = (blockIdx.x / tc) << 5, c0 = (blockIdx.x % tc) << 5;
  int tx = threadIdx.x & 31, ty = threadIdx.x >> 5;
  #pragma unroll
  for (int q = 0; q < 4; ++q) {
    int r = ty + q * 8;
    tile[r][tx] = in[(size_t)(r0 + r) * C + c0 + tx];
  }
  __syncthreads();
  #pragma unroll
  for (int q = 0; q < 4; ++q) {
    int r = ty + q * 8;
    out[(size_t)(c0 + r) * R + r0 + tx] = f2b(tile[tx][r]);
  }
}

__global__ void __launch_bounds__(256)
k_init(const float* __restrict__ hidden, float* h, u16* hs_hi, u16* hs_lo)
{
  int i = blockIdx.x * 256 + threadIdx.x;
  if (i < B_ * H_) {
    float x = hidden[i];
    h[i] = x;
    u16 a = f2b(x);
    hs_hi[i] = a;            // slot 0
    hs_lo[i] = f2b(x - b2f(a));
  }
}

extern "C" void kernel_launch(void* const* d_in, const int* in_sizes, int n_in,
                              void* d_out, int out_size, void* d_ws, size_t ws_size,
                              hipStream_t stream) {
  (void)in_sizes; (void)n_in; (void)out_size; (void)ws_size;
  const float* enc    = (const float*)d_in[0];
  const float* hidden = (const float*)d_in[1];
  const float* tgt    = (const float*)d_in[2];
  const float* Watt   = (const float*)d_in[3];
  const float* batt   = (const float*)d_in[4];
  const float* Wcomb  = (const float*)d_in[5];
  const float* bcomb  = (const float*)d_in[6];
  const float* Wih    = (const float*)d_in[7];
  const float* bih    = (const float*)d_in[8];
  const float* Whh    = (const float*)d_in[9];
  const float* bhh    = (const float*)d_in[10];
  const float* Wout   = (const float*)d_in[11];
  const float* bout   = (const float*)d_in[12];

  size_t off = 0;
  char* base = (char*)d_ws;
  auto alloc = [&](size_t bytes) -> void* {
    void* p = base + off;
    off += (bytes + 255) & ~(size_t)255;
    return p;
  };
  u32*   bar    = (u32*)  alloc(1024);          // dense 256 u32 slots
  float* h      = (float*)alloc(B_ * H_ * 4);
  float* logit  = (float*)alloc(B_ * A_ * 4);
  float* gh     = (float*)alloc((size_t)3 * H_ * B_ * 4);
  float* ldec_all = (float*)alloc((size_t)T_ * B_ * A_ * 4);     // 16MB
  float* g_all    = (float*)alloc((size_t)T_ * B_ * H_ * 4);     // 16MB
  u16*   hs_hi  = (u16*)  alloc((size_t)(T_ + 1) * B_ * H_ * 2); // rotating slots
  u16*   hs_lo  = (u16*)  alloc((size_t)(T_ + 1) * B_ * H_ * 2);
  u16*   tgt_hi = (u16*)  alloc((size_t)B_ * T_ * H_ * 2);
  u16*   tgt_lo = (u16*)  alloc((size_t)B_ * T_ * H_ * 2);
  u16*   WattT  = (u16*)  alloc((size_t)2048 * 1024 * 2);
  u16*   Whh_b  = (u16*)  alloc((size_t)3 * H_ * H_ * 2);
  u16*   Wih_b  = (u16*)  alloc((size_t)3 * H_ * H_ * 2);
  u16*   WcombT = (u16*)  alloc((size_t)1024 * 1536 * 2);
  u16*   Wc_ctxT= (u16*)  alloc((size_t)1024 * 512 * 2);
  u16*   WoutT  = (u16*)  alloc((size_t)512 * 1024 * 2);

  hipMemsetAsync(bar, 0, 1024, stream);

  k_cvt_split<<<2048, 256, 0, stream>>>(tgt, tgt_hi, tgt_lo, B_ * T_ * H_);
  k_cvt<<<2048, 256, 0, stream>>>(Whh, Whh_b, 3 * H_ * H_);
  k_cvt<<<2048, 256, 0, stream>>>(Wih, Wih_b, 3 * H_ * H_);
  k_tr<<<64 * 32, 256, 0, stream>>>(Watt, WattT, 2048, 1024);
  k_tr<<<48 * 32, 256, 0, stream>>>(Wcomb, WcombT, 1536, 1024);
  k_tr<<<16 * 32, 256, 0, stream>>>(Wcomb + (size_t)1024 * H_, Wc_ctxT, 512, 1024);
  k_tr<<<32 * 16, 256, 0, stream>>>(Wout, WoutT, 1024, 512);
  k_init<<<128, 256, 0, stream>>>(hidden, h, hs_hi, hs_lo);

  // dec contributions precomputed for all t (bias folded; t=0 -> bias only)
  dec_gemm<<<2048, 256, 0, stream>>>(tgt_hi, tgt_lo, WattT, 2048UL, batt, ldec_all);
  dec_gemm<<<2048, 256, 0, stream>>>(tgt_hi, tgt_lo, WcombT, 1536UL, bcomb, g_all);

  hipFuncSetAttribute((const void*)dec_persist,
                      hipFuncAttributeMaxDynamicSharedMemorySize, DSMEM_BYTES);

  dec_persist<<<NBLK, NTH, DSMEM_BYTES, stream>>>(WattT, Whh_b, Wih_b, Wc_ctxT, enc,
                                                  bih, bhh, ldec_all,
                                                  h, logit, gh, g_all,
                                                  hs_hi, hs_lo, bar);
  out_gemm<<<1024, 256, 0, stream>>>(hs_hi + B_ * H_, WoutT, bout, (float*)d_out);
  hlast_copy<<<128, 256, 0, stream>>>(h, (float*)d_out);
}

// Round 13
// 3935.658 us; speedup vs baseline: 1.4863x; 1.4863x over previous
//
#include <hip/hip_runtime.h>

typedef unsigned short u16;
typedef unsigned int u32;
typedef unsigned long long u64;
typedef short v8s __attribute__((ext_vector_type(8)));
typedef float v4f __attribute__((ext_vector_type(4)));
typedef int v4i __attribute__((ext_vector_type(4)));

#define MFMA16(a, b, c) __builtin_amdgcn_mfma_f32_16x16x32_bf16((a), (b), (c), 0, 0, 0)

#define B_ 32
#define T_ 128
#define H_ 1024
#define A_ 1024
#define E_ 512
#define V_ 512
#define NBLK 256
#define NTH 512
#define NSLOT 32
#define ENC_LDS_BYTES 131072
#define SCRATCH_BYTES 28672
#define DSMEM_BYTES (ENC_LDS_BYTES + SCRATCH_BYTES)

__device__ __forceinline__ float b2f(u16 u) {
  union { u32 u; float f; } c; c.u = ((u32)u) << 16; return c.f;
}
__device__ __forceinline__ u16 f2b(float f) {
  union { float f; u32 u; } c; c.f = f;
  u32 x = c.u;
  x += 0x7fffu + ((x >> 16) & 1u);
  return (u16)(x >> 16);
}

// ---- relaxed agent-scope (sc1) stores / RMW ----
__device__ __forceinline__ void ato_st(u32* p, u32 v) {
  __hip_atomic_store(p, v, __ATOMIC_RELAXED, __HIP_MEMORY_SCOPE_AGENT);
}
__device__ __forceinline__ void ato_stf(float* p, float v) {
  union { float f; u32 u; } c; c.f = v; ato_st((u32*)p, c.u);
}
__device__ __forceinline__ void ato_addf(float* p, float v) {
  __hip_atomic_fetch_add(p, v, __ATOMIC_RELAXED, __HIP_MEMORY_SCOPE_AGENT);
}

// ---- issue-early sc1 loads (L2-bypass, compiler-invisible -> pipelined) ----
__device__ __forceinline__ v4i ld16_sc1(const void* p) {
  v4i r;
  asm volatile("global_load_dwordx4 %0, %1, off sc1" : "=v"(r) : "v"(p));
  return r;
}
__device__ __forceinline__ float ld4_sc1(const void* p) {
  float r;
  asm volatile("global_load_dword %0, %1, off sc1" : "=v"(r) : "v"(p));
  return r;
}
__device__ __forceinline__ void wait_vm0() {
  asm volatile("s_waitcnt vmcnt(0)" ::: "memory");
  __builtin_amdgcn_sched_barrier(0);
}
__device__ __forceinline__ v8s as8(v4i x) { union { v4i a; v8s b; } u; u.a = x; return u.b; }
// 8 f32 (bias folded) -> relu -> split bf16 hi/lo fragments
__device__ __forceinline__ void cvt8(v4i qa, v4i qb, v8s& hi, v8s& lo) {
  union { v4i q; float f[4]; } a, b;
  a.q = qa; b.q = qb;
  float v[8] = {a.f[0], a.f[1], a.f[2], a.f[3], b.f[0], b.f[1], b.f[2], b.f[3]};
  u16 hh[8], ll[8];
  #pragma unroll
  for (int i = 0; i < 8; ++i) {
    float x = fmaxf(v[i], 0.f);
    u16 hv = f2b(x);
    hh[i] = hv; ll[i] = f2b(x - b2f(hv));
  }
  hi = *(v8s*)hh; lo = *(v8s*)ll;
}

// ---- split semaphores (spread slots; relaxed; vmcnt-drained posts) ----
// post: every wave drains vmcnt, block syncs, thread0 stores its slot.
__device__ __forceinline__ void post_sem(u32* slots, int idx, u32 ep) {
  asm volatile("s_waitcnt vmcnt(0)" ::: "memory");
  __syncthreads();
  if (threadIdx.x == 0)
    __hip_atomic_store(slots + idx * NSLOT, ep, __ATOMIC_RELAXED, __HIP_MEMORY_SCOPE_AGENT);
}
// wait: threads 0..n-1 each poll one spread slot; block-sync on exit.
__device__ __forceinline__ void wait_sem(const u32* slots, int n, u32 ep) {
  if (threadIdx.x < (unsigned)n) {
    while (__hip_atomic_load(slots + threadIdx.x * NSLOT, __ATOMIC_RELAXED, __HIP_MEMORY_SCOPE_AGENT) < ep)
      __builtin_amdgcn_s_sleep(8);
  }
  __syncthreads();
  asm volatile("" ::: "memory");
}

// GEMM inner (plain loads; used by P3 dec tiles on read-only tgt)
__device__ __forceinline__ void gemm_nk(const u16* ah, const u16* al, size_t mstr,
                                        const u16* bp, int nk, v4f& c0, v4f& c1) {
  #pragma unroll 2
  for (int i = 0; i < nk; ++i) {
    v8s b   = *(const v8s*)(bp);
    v8s a0h = *(const v8s*)(ah);
    v8s a1h = *(const v8s*)(ah + mstr);
    v8s a0l = *(const v8s*)(al);
    v8s a1l = *(const v8s*)(al + mstr);
    c0 = MFMA16(a0h, b, c0);
    c1 = MFMA16(a1h, b, c1);
    c0 = MFMA16(a0l, b, c0);
    c1 = MFMA16(a1l, b, c1);
    ah += 32; al += 32; bp += 32;
  }
}

// partial layout: [wave][lane][8] floats
__device__ __forceinline__ void red_store2(float* part, int wv, int lane, v4f c0, v4f c1) {
  float* p = part + (wv * 64 + lane) * 8;
  #pragma unroll
  for (int r = 0; r < 4; ++r) { p[r] = c0[r]; p[4 + r] = c1[r]; }
}
__device__ __forceinline__ float red_sum2(const float* part, int o) {
  int m = o >> 4, n = o & 15;
  int lane = (((m & 15) >> 2) << 4) + n;
  int idx = ((m >> 4) << 2) + (m & 3);
  float s = 0.f;
  #pragma unroll
  for (int w = 0; w < 8; ++w) s += part[(w * 64 + lane) * 8 + idx];
  return s;
}

__global__ void __launch_bounds__(NTH, 1)
dec_persist(const u16* __restrict__ tgt_hi, const u16* __restrict__ tgt_lo,
            const u16* __restrict__ WattT, const u16* __restrict__ Whh_b,
            const u16* __restrict__ Wih_b, const u16* __restrict__ WcombT,
            const u16* __restrict__ Wc_ctxT,
            const float* __restrict__ enc_f,
            const float* __restrict__ batt, const float* __restrict__ bcomb,
            const float* __restrict__ bih, const float* __restrict__ bhh,
            float* h, float* logit, float* gh, float* g_acc, float* logit_dec,
            u16* hbf_hi, u16* hbf_lo, u16* hseqb, u32* sems)
{
  const int tid = threadIdx.x;
  const int bid = blockIdx.x;
  const int lane = tid & 63;
  const int wv = tid >> 6;
  const int ln = lane & 15;
  const int kq8 = (lane >> 4) * 8;

  u32* S1 = sems;                       // 64 slots  (logit producers)
  u32* S2 = sems + 64 * NSLOT;          // 256 slots (all, after P2)
  u32* S3 = sems + (64 + 256) * NSLOT;  // 192 slots (gates + dec writers)

  extern __shared__ __align__(16) unsigned char dsm[];
  u16* lds_enc = (u16*)dsm;                        // [1024][64] bf16 = 128KB
  float* scratch = (float*)(dsm + ENC_LDS_BYTES);  // 28KB

  // ---- one-time: stage this block's enc slice (b=bid>>3, e0=(bid&7)*64) ----
  {
    int b = bid >> 3, e0 = (bid & 7) * 64;
    const float* src = enc_f + (size_t)b * A_ * E_ + e0 + (tid & 7) * 8;
    int seg = (tid & 7) * 8;
    for (int i = 0; i < 16; ++i) {
      int row = i * 64 + (tid >> 3);
      const float* sp = src + (size_t)row * E_;
      float4 a = *(const float4*)sp;
      float4 bq = *(const float4*)(sp + 4);
      u16 tmp[8] = {f2b(a.x), f2b(a.y), f2b(a.z), f2b(a.w),
                    f2b(bq.x), f2b(bq.y), f2b(bq.z), f2b(bq.w)};
      *(v8s*)(lds_enc + row * 64 + seg) = *(v8s*)tmp;
    }
  }

  for (int t = 0; t < T_; ++t) {
    u32 ep = (u32)(t + 1);
    // ==== P1: logits-h (blocks 0-63) + gh (64-255); issue-early A loads ====
    {
      float* part = scratch;
      size_t a0 = (size_t)ln * H_ + wv * 128 + kq8;
      v4i ah0[4], ah1[4], al0[4], al1[4];
      #pragma unroll
      for (int i = 0; i < 4; ++i) {
        ah0[i] = ld16_sc1(hbf_hi + a0 + i * 32);
        ah1[i] = ld16_sc1(hbf_hi + a0 + 16 * H_ + i * 32);
        al0[i] = ld16_sc1(hbf_lo + a0 + i * 32);
        al1[i] = ld16_sc1(hbf_lo + a0 + 16 * H_ + i * 32);
      }
      float ldec = 0.f;
      const u16* bp;
      int n0;
      if (bid < 64) {
        // bias-seed next-step g accumulator (512 floats per block)
        int gi = bid * 512 + tid;
        ato_stf(&g_acc[((t + 1) & 1) * (B_ * H_) + gi], bcomb[gi & (H_ - 1)]);
        n0 = bid * 16;
        ldec = ld4_sc1(&logit_dec[(t & 1) * (B_ * A_) + (tid >> 4) * A_ + n0 + (tid & 15)]);
        bp = WattT + (size_t)(n0 + ln) * 2048 + 1024 + wv * 128 + kq8;
      } else {
        n0 = (bid - 64) * 16;
        bp = Whh_b + (size_t)(n0 + ln) * H_ + wv * 128 + kq8;
      }
      v8s wb[4];
      #pragma unroll
      for (int i = 0; i < 4; ++i) wb[i] = *(const v8s*)(bp + i * 32);
      v4f c0 = {0.f, 0.f, 0.f, 0.f}, c1 = {0.f, 0.f, 0.f, 0.f};
      wait_vm0();
      #pragma unroll
      for (int i = 0; i < 4; ++i) {
        c0 = MFMA16(as8(ah0[i]), wb[i], c0);
        c1 = MFMA16(as8(ah1[i]), wb[i], c1);
        c0 = MFMA16(as8(al0[i]), wb[i], c0);
        c1 = MFMA16(as8(al1[i]), wb[i], c1);
      }
      red_store2(part, wv, lane, c0, c1);
      __syncthreads();
      {
        float s = red_sum2(part, tid);
        int m = tid >> 4, n = tid & 15;
        if (bid < 64) {
          ato_stf(&logit[m * A_ + n0 + n], s + ldec);   // batt folded into logit_dec
        } else {
          ato_stf(&gh[(size_t)(n0 + n) * 32 + m], s + bhh[n0 + n]);
        }
      }
    }
    // B1: only logit blocks post; everyone waits on 64 slots
    if (bid < 64) post_sem(S1, bid, ep);
    wait_sem(S1, 64, ep);

    // ==== P2: softmax + ctx (LDS enc) + coalesced GEMV add into g_acc[t] ====
    {
      float* p    = scratch;            // [1024]
      float* part = scratch + 1024;     // [64][64]
      float* red  = scratch + 5120;     // [16]
      float* sctx = scratch + 5136;     // [64]
      int b = bid >> 3, es = bid & 7;
      float v1 = ld4_sc1(&logit[b * A_ + tid]);
      float v2 = ld4_sc1(&logit[b * A_ + 512 + tid]);
      wait_vm0();
      float mx = fmaxf(v1, v2);
      #pragma unroll
      for (int off = 32; off; off >>= 1) mx = fmaxf(mx, __shfl_xor(mx, off));
      if (lane == 0) red[wv] = mx;
      __syncthreads();
      float mfull = red[0];
      #pragma unroll
      for (int q = 1; q < 8; ++q) mfull = fmaxf(mfull, red[q]);
      float e1 = __expf(v1 - mfull), e2 = __expf(v2 - mfull);
      p[tid] = e1; p[512 + tid] = e2;
      float sm = e1 + e2;
      #pragma unroll
      for (int off = 32; off; off >>= 1) sm += __shfl_xor(sm, off);
      if (lane == 0) red[8 + wv] = sm;
      __syncthreads();
      float ssum = red[8];
      #pragma unroll
      for (int q = 1; q < 8; ++q) ssum += red[8 + q];
      float inv = 1.f / ssum;

      int le = lane & 7, lr = lane >> 3;
      float acc[8] = {0.f, 0.f, 0.f, 0.f, 0.f, 0.f, 0.f, 0.f};
      #pragma unroll 4
      for (int i = 0; i < 16; ++i) {
        int l = i * 64 + wv * 8 + lr;
        v8s w = *(const v8s*)(lds_enc + l * 64 + le * 8);
        float pv = p[l];
        #pragma unroll
        for (int r = 0; r < 8; ++r) acc[r] += pv * b2f((u16)w[r]);
      }
      float* pp = part + ((wv * 8 + lr) * 8 + le) * 8;
      #pragma unroll
      for (int r = 0; r < 8; ++r) pp[r] = acc[r];
      __syncthreads();
      if (tid < 64) {
        int eo = tid >> 3, r = tid & 7;
        float s = 0.f;
        #pragma unroll
        for (int q = 0; q < 64; ++q) s += part[q * 64 + eo * 8 + r];
        sctx[tid] = s * inv;
      }
      __syncthreads();
      // GEMV (transposed weights): thread -> cols 2*tid, 2*tid+1; contiguous e
      {
        const u16* w0 = Wc_ctxT + (size_t)(2 * tid) * E_ + es * 64;
        const u16* w1 = w0 + E_;
        float a0 = 0.f, a1 = 0.f;
        #pragma unroll
        for (int i = 0; i < 8; ++i) {
          v8s q0 = *(const v8s*)(w0 + i * 8);
          v8s q1 = *(const v8s*)(w1 + i * 8);
          #pragma unroll
          for (int r = 0; r < 8; ++r) {
            float pv = sctx[i * 8 + r];
            a0 += pv * b2f((u16)q0[r]);
            a1 += pv * b2f((u16)q1[r]);
          }
        }
        float* gp = g_acc + (t & 1) * (B_ * H_) + b * H_ + 2 * tid;
        ato_addf(gp, a0);
        ato_addf(gp + 1, a1);
      }
    }
    // B2: everyone posts; ONLY gates (0-63) must wait for all 256
    post_sem(S2, bid, ep);
    if (bid < 64) wait_sem(S2, NBLK, ep);

    // ==== P3: gates (0-63) + logit_dec t+1 (64-127) + g_dec t+1 add (128-191) ====
    {
      if (bid < 64) {
        float* part = scratch;            // [8][64][12] = 24KB per pass
        float* hx   = scratch + 6144;     // [32][16]
        int j0 = bid * 16;
        const float* gbase = g_acc + (t & 1) * (B_ * H_);
        int koff0 = wv * 128 + kq8;
        v4i gr0[8], gr1[8];
        #pragma unroll
        for (int i = 0; i < 4; ++i) {
          const float* p0 = gbase + (size_t)ln * H_ + koff0 + i * 32;
          const float* p1 = gbase + (size_t)(ln + 16) * H_ + koff0 + i * 32;
          gr0[2 * i]     = ld16_sc1(p0);
          gr0[2 * i + 1] = ld16_sc1(p0 + 4);
          gr1[2 * i]     = ld16_sc1(p1);
          gr1[2 * i + 1] = ld16_sc1(p1 + 4);
        }
        const u16* bp0 = Wih_b + (size_t)(j0 + ln) * H_ + koff0;
        const u16* bp1 = bp0 + (size_t)H_ * H_;
        const u16* bp2 = bp0 + (size_t)2 * H_ * H_;
        v8s wb0[4], wb1[4], wb2[4];
        #pragma unroll
        for (int i = 0; i < 4; ++i) {
          wb0[i] = *(const v8s*)(bp0 + i * 32);
          wb1[i] = *(const v8s*)(bp1 + i * 32);
          wb2[i] = *(const v8s*)(bp2 + i * 32);
        }
        v4f c00 = {0.f,0.f,0.f,0.f}, c01 = c00, c02 = c00, c10 = c00, c11 = c00, c12 = c00;
        wait_vm0();
        #pragma unroll
        for (int i = 0; i < 4; ++i) {
          v8s a0h, a0l, a1h, a1l;
          cvt8(gr0[2 * i], gr0[2 * i + 1], a0h, a0l);
          cvt8(gr1[2 * i], gr1[2 * i + 1], a1h, a1l);
          c00 = MFMA16(a0h, wb0[i], c00); c00 = MFMA16(a0l, wb0[i], c00);
          c01 = MFMA16(a0h, wb1[i], c01); c01 = MFMA16(a0l, wb1[i], c01);
          c02 = MFMA16(a0h, wb2[i], c02); c02 = MFMA16(a0l, wb2[i], c02);
          c10 = MFMA16(a1h, wb0[i], c10); c10 = MFMA16(a1l, wb0[i], c10);
          c11 = MFMA16(a1h, wb1[i], c11); c11 = MFMA16(a1l, wb1[i], c11);
          c12 = MFMA16(a1h, wb2[i], c12); c12 = MFMA16(a1l, wb2[i], c12);
        }
        // gate-side loads issued early (consumed after LDS reductions)
        float hr0 = 0.f, hz0 = 0.f, hn0 = 0.f, hr1 = 0.f, hz1 = 0.f, hn1 = 0.f;
        float ho0 = 0.f, ho1 = 0.f;
        int obl = tid >> 4, jj = tid & 15, j = j0 + jj;
        if (tid < 256) {
          hr0 = ld4_sc1(&gh[(size_t)j * 32 + obl]);
          hz0 = ld4_sc1(&gh[(size_t)(H_ + j) * 32 + obl]);
          hn0 = ld4_sc1(&gh[(size_t)(2 * H_ + j) * 32 + obl]);
          hr1 = ld4_sc1(&gh[(size_t)j * 32 + 16 + obl]);
          hz1 = ld4_sc1(&gh[(size_t)(H_ + j) * 32 + 16 + obl]);
          hn1 = ld4_sc1(&gh[(size_t)(2 * H_ + j) * 32 + 16 + obl]);
          ho0 = h[obl * H_ + j];
          ho1 = h[(obl + 16) * H_ + j];
        }
        float bi_r = 0.f, bi_z = 0.f, bi_n = 0.f;
        if (tid < 256) {
          bi_r = bih[j]; bi_z = bih[H_ + j]; bi_n = bih[2 * H_ + j];
        }
        #pragma unroll
        for (int pass = 0; pass < 2; ++pass) {
          float* pp = part + (wv * 64 + lane) * 12;
          if (pass == 0) {
            #pragma unroll
            for (int r = 0; r < 4; ++r) { pp[r] = c00[r]; pp[4 + r] = c01[r]; pp[8 + r] = c02[r]; }
          } else {
            #pragma unroll
            for (int r = 0; r < 4; ++r) { pp[r] = c10[r]; pp[4 + r] = c11[r]; pp[8 + r] = c12[r]; }
          }
          __syncthreads();
          if (tid < 256) {
            if (pass == 0) wait_vm0();
            int ob = pass * 16 + obl;
            int lanei = ((obl >> 2) << 4) + jj;
            int rg = obl & 3;
            float ir = 0.f, iz = 0.f, in_ = 0.f;
            #pragma unroll
            for (int w = 0; w < 8; ++w) {
              const float* q = part + (w * 64 + lanei) * 12;
              ir += q[rg]; iz += q[4 + rg]; in_ += q[8 + rg];
            }
            ir += bi_r; iz += bi_z; in_ += bi_n;
            float hr = pass ? hr1 : hr0;
            float hz = pass ? hz1 : hz0;
            float hn = pass ? hn1 : hn0;
            float ho = pass ? ho1 : ho0;
            float r = 1.f / (1.f + __expf(-(ir + hr)));
            float z = 1.f / (1.f + __expf(-(iz + hz)));
            float n = tanhf(in_ + r * hn);
            float hnew = (1.f - z) * n + z * ho;
            h[ob * H_ + j] = hnew;
            hx[ob * 16 + jj] = hnew;
          }
          __syncthreads();
        }
        if (tid < 256) {
          int ob2 = tid >> 3, j2 = (tid & 7) * 2;
          float v0 = hx[ob2 * 16 + j2], v1 = hx[ob2 * 16 + j2 + 1];
          u16 h0 = f2b(v0), h1 = f2b(v1);
          u16 l0 = f2b(v0 - b2f(h0)), l1 = f2b(v1 - b2f(h1));
          int idx = ob2 * H_ + j0 + j2;
          u32 hp = (u32)h0 | ((u32)h1 << 16);
          ato_st((u32*)(hbf_hi + idx), hp);
          ato_st((u32*)(hbf_lo + idx), (u32)l0 | ((u32)l1 << 16));
          *(u32*)(hseqb + ((size_t)t * 32 + ob2) * H_ + j0 + j2) = hp;
        }
      } else if (bid < 128) {
        if (t < T_ - 1) {
          float* part = scratch;
          int n0 = (bid - 64) * 16;
          v4f c0 = {0.f, 0.f, 0.f, 0.f}, c1 = {0.f, 0.f, 0.f, 0.f};
          size_t abase = ((size_t)ln * T_ + t) * H_ + wv * 128 + kq8;
          const u16* bp = WattT + (size_t)(n0 + ln) * 2048 + wv * 128 + kq8;
          gemm_nk(tgt_hi + abase, tgt_lo + abase, (size_t)16 * T_ * H_, bp, 4, c0, c1);
          red_store2(part, wv, lane, c0, c1);
          __syncthreads();
          int m = tid >> 4, n = tid & 15;
          ato_stf(&logit_dec[((t + 1) & 1) * (B_ * A_) + m * A_ + n0 + n],
                  red_sum2(part, tid) + batt[n0 + n]);
        }
      } else if (bid < 192) {
        if (t < T_ - 1) {
          float* part = scratch;
          int n0 = (bid - 128) * 16;
          v4f c0 = {0.f, 0.f, 0.f, 0.f}, c1 = {0.f, 0.f, 0.f, 0.f};
          size_t abase = ((size_t)ln * T_ + t) * H_ + wv * 128 + kq8;
          const u16* bp = WcombT + (size_t)(n0 + ln) * 1536 + wv * 128 + kq8;
          gemm_nk(tgt_hi + abase, tgt_lo + abase, (size_t)16 * T_ * H_, bp, 4, c0, c1);
          red_store2(part, wv, lane, c0, c1);
          __syncthreads();
          int m = tid >> 4, n = tid & 15;
          ato_addf(&g_acc[((t + 1) & 1) * (B_ * H_) + m * H_ + n0 + n], red_sum2(part, tid));
        }
      }
    }
    // B3: gates + dec writers (0-191) post; everyone waits on 192 slots
    if (bid < 192) post_sem(S3, bid, ep);
    wait_sem(S3, 192, ep);
  }
}

// out[b][t][v] = hseqb[t*32+b][:] @ WoutT^T + bout   (M=4096, N=512, K=1024)
__global__ void __launch_bounds__(256, 2)
out_gemm(const u16* __restrict__ hseqb, const u16* __restrict__ WoutT,
         const float* __restrict__ bout, float* __restrict__ out)
{
  int tid = threadIdx.x, lane = tid & 63, wv = tid >> 6;
  int ln = lane & 15, kq8 = (lane >> 4) * 8;
  int m0 = (blockIdx.x >> 3) * 32;
  int n0 = (blockIdx.x & 7) * 64 + wv * 16;
  v4f c0 = {0.f, 0.f, 0.f, 0.f}, c1 = {0.f, 0.f, 0.f, 0.f};
  const u16* ap = hseqb + (size_t)(m0 + ln) * 1024 + kq8;
  const u16* bp = WoutT + (size_t)(n0 + ln) * 1024 + kq8;
  for (int i = 0; i < 32; ++i) {
    v8s b = *(const v8s*)bp;
    v8s a0 = *(const v8s*)ap;
    v8s a1 = *(const v8s*)(ap + 16 * 1024);
    c0 = MFMA16(a0, b, c0);
    c1 = MFMA16(a1, b, c1);
    ap += 32; bp += 32;
  }
  int v = n0 + ln;
  float bo = bout[v];
  int rbase = (lane >> 4) * 4;
  #pragma unroll
  for (int rg = 0; rg < 4; ++rg) {
    int m = m0 + rbase + rg;
    out[((size_t)(m & 31) * T_ + (m >> 5)) * V_ + v] = c0[rg] + bo;
    int m2 = m + 16;
    out[((size_t)(m2 & 31) * T_ + (m2 >> 5)) * V_ + v] = c1[rg] + bo;
  }
}

__global__ void __launch_bounds__(256)
hlast_copy(const float* __restrict__ h, float* __restrict__ out)
{
  int i = blockIdx.x * 256 + threadIdx.x;
  if (i < B_ * H_) out[(size_t)B_ * T_ * V_ + i] = h[i];
}

// ---------------- prep kernels ----------------
__global__ void __launch_bounds__(256)
k_cvt(const float* __restrict__ in, u16* __restrict__ out, int n)
{
  int stride = gridDim.x * 256;
  for (int i = blockIdx.x * 256 + threadIdx.x; i < n; i += stride) out[i] = f2b(in[i]);
}

__global__ void __launch_bounds__(256)
k_cvt_split(const float* __restrict__ in, u16* __restrict__ hi, u16* __restrict__ lo, int n)
{
  int stride = gridDim.x * 256;
  for (int i = blockIdx.x * 256 + threadIdx.x; i < n; i += stride) {
    float x = in[i];
    u16 a = f2b(x);
    hi[i] = a;
    lo[i] = f2b(x - b2f(a));
  }
}

// out[c][r] = bf16(in[r][c]); R, C multiples of 32
__global__ void __launch_bounds__(256)
k_tr(const float* __restrict__ in, u16* __restrict__ out, int R, int C)
{
  __shared__ float tile[32][33];
  int tc = C >> 5;
  int r0 = (blockIdx.x / tc) << 5, c0 = (blockIdx.x % tc) << 5;
  int tx = threadIdx.x & 31, ty = threadIdx.x >> 5;
  #pragma unroll
  for (int q = 0; q < 4; ++q) {
    int r = ty + q * 8;
    tile[r][tx] = in[(size_t)(r0 + r) * C + c0 + tx];
  }
  __syncthreads();
  #pragma unroll
  for (int q = 0; q < 4; ++q) {
    int r = ty + q * 8;
    out[(size_t)(c0 + r) * R + r0 + tx] = f2b(tile[tx][r]);
  }
}

__global__ void __launch_bounds__(256)
k_init(const float* __restrict__ hidden, const float* __restrict__ bcomb,
       float* h, u16* hhi, u16* hlo, float* g_acc)
{
  int i = blockIdx.x * 256 + threadIdx.x;
  if (i < B_ * H_) {
    float x = hidden[i];
    h[i] = x;
    u16 a = f2b(x);
    hhi[i] = a;
    hlo[i] = f2b(x - b2f(a));
    g_acc[i] = bcomb[i & (H_ - 1)];  // bias-seed buffer 0 (t=0)
  }
}

extern "C" void kernel_launch(void* const* d_in, const int* in_sizes, int n_in,
                              void* d_out, int out_size, void* d_ws, size_t ws_size,
                              hipStream_t stream) {
  (void)in_sizes; (void)n_in; (void)out_size; (void)ws_size;
  const float* enc    = (const float*)d_in[0];
  const float* hidden = (const float*)d_in[1];
  const float* tgt    = (const float*)d_in[2];
  const float* Watt   = (const float*)d_in[3];
  const float* batt   = (const float*)d_in[4];
  const float* Wcomb  = (const float*)d_in[5];
  const float* bcomb  = (const float*)d_in[6];
  const float* Wih    = (const float*)d_in[7];
  const float* bih    = (const float*)d_in[8];
  const float* Whh    = (const float*)d_in[9];
  const float* bhh    = (const float*)d_in[10];
  const float* Wout   = (const float*)d_in[11];
  const float* bout   = (const float*)d_in[12];

  size_t off = 0;
  char* base = (char*)d_ws;
  auto alloc = [&](size_t bytes) -> void* {
    void* p = base + off;
    off += (bytes + 255) & ~(size_t)255;
    return p;
  };
  size_t sem_bytes = (size_t)(64 + 256 + 192) * NSLOT * 4;
  u32*   sems   = (u32*)  alloc(sem_bytes);
  float* h      = (float*)alloc(B_ * H_ * 4);
  float* logit  = (float*)alloc(B_ * A_ * 4);
  float* gh     = (float*)alloc((size_t)3 * H_ * B_ * 4);
  float* g_acc  = (float*)alloc((size_t)2 * B_ * H_ * 4);
  float* logit_dec = (float*)alloc((size_t)2 * B_ * A_ * 4);
  u16*   hbf_hi = (u16*)  alloc(B_ * H_ * 2);
  u16*   hbf_lo = (u16*)  alloc(B_ * H_ * 2);
  u16*   hseqb  = (u16*)  alloc((size_t)T_ * B_ * H_ * 2);
  u16*   tgt_hi = (u16*)  alloc((size_t)B_ * T_ * H_ * 2);
  u16*   tgt_lo = (u16*)  alloc((size_t)B_ * T_ * H_ * 2);
  u16*   WattT  = (u16*)  alloc((size_t)2048 * 1024 * 2);
  u16*   Whh_b  = (u16*)  alloc((size_t)3 * H_ * H_ * 2);
  u16*   Wih_b  = (u16*)  alloc((size_t)3 * H_ * H_ * 2);
  u16*   WcombT = (u16*)  alloc((size_t)1024 * 1536 * 2);
  u16*   Wc_ctxT= (u16*)  alloc((size_t)1024 * 512 * 2);
  u16*   WoutT  = (u16*)  alloc((size_t)512 * 1024 * 2);

  hipMemsetAsync(sems, 0, sem_bytes, stream);
  hipMemsetAsync(logit_dec, 0, (size_t)2 * B_ * A_ * 4, stream);

  k_cvt_split<<<2048, 256, 0, stream>>>(tgt, tgt_hi, tgt_lo, B_ * T_ * H_);
  k_cvt<<<2048, 256, 0, stream>>>(Whh, Whh_b, 3 * H_ * H_);
  k_cvt<<<2048, 256, 0, stream>>>(Wih, Wih_b, 3 * H_ * H_);
  k_tr<<<64 * 32, 256, 0, stream>>>(Watt, WattT, 2048, 1024);
  k_tr<<<48 * 32, 256, 0, stream>>>(Wcomb, WcombT, 1536, 1024);
  k_tr<<<16 * 32, 256, 0, stream>>>(Wcomb + (size_t)1024 * H_, Wc_ctxT, 512, 1024);
  k_tr<<<32 * 16, 256, 0, stream>>>(Wout, WoutT, 1024, 512);
  k_init<<<128, 256, 0, stream>>>(hidden, bcomb, h, hbf_hi, hbf_lo, g_acc);

  hipFuncSetAttribute((const void*)dec_persist,
                      hipFuncAttributeMaxDynamicSharedMemorySize, DSMEM_BYTES);

  dec_persist<<<NBLK, NTH, DSMEM_BYTES, stream>>>(tgt_hi, tgt_lo, WattT, Whh_b, Wih_b,
                                                  WcombT, Wc_ctxT, enc,
                                                  batt, bcomb, bih, bhh,
                                                  h, logit, gh, g_acc, logit_dec,
                                                  hbf_hi, hbf_lo, hseqb, sems);
  out_gemm<<<1024, 256, 0, stream>>>(hseqb, WoutT, bout, (float*)d_out);
  hlast_copy<<<128, 256, 0, stream>>>(h, (float*)d_out);
}